// Round 4
// baseline (329.420 us; speedup 1.0000x reference)
//
#include <hip/hip_runtime.h>
#include <cstdint>
#include <cstddef>

using f16   = _Float16;
using half8 = __attribute__((ext_vector_type(8))) _Float16;
using f32x4 = __attribute__((ext_vector_type(4))) float;

#define DINL __device__ __forceinline__

// global -> LDS async, 16B per lane. LDS dest wave-uniform base + lane*16.
DINL void gload_lds16(const void* gptr, void* lptr) {
  __builtin_amdgcn_global_load_lds(
      reinterpret_cast<const __attribute__((address_space(1))) uint32_t*>(
          reinterpret_cast<uintptr_t>(gptr)),
      reinterpret_cast<__attribute__((address_space(3))) uint32_t*>(
          reinterpret_cast<uintptr_t>(lptr)),
      16, 0, 0);
}

// x -> 8 fp16 channels [B0..B5 uniform cubic B-spline, silu(x), 0]. Verified r1/r2.
DINL half8 expand8(float x) {
  float xs = (x + 3.0f) * 1.5f;
  float mf = floorf(xs);
  int   m  = (int)mf;
  float p0 = 0.f, p1 = 0.f, p2 = 0.f, p3 = 0.f;
  if (m >= 0 && m <= 8) {
    float u = xs - mf, u2 = u * u, u3 = u2 * u, um = 1.0f - u;
    p3 = u3 * (1.0f / 6.0f);
    p2 = (1.0f + 3.0f * u + 3.0f * u2 - 3.0f * u3) * (1.0f / 6.0f);
    p1 = (4.0f - 6.0f * u2 + 3.0f * u3) * (1.0f / 6.0f);
    p0 = um * um * um * (1.0f / 6.0f);
  }
  half8 o;
#pragma unroll
  for (int j = 0; j < 6; ++j) {
    int dmj = m - j;
    float v = (dmj == 0) ? p3 : (dmj == 1) ? p2 : (dmj == 2) ? p1
            : (dmj == 3) ? p0 : 0.0f;
    o[j] = (f16)v;
  }
  o[6] = (f16)(x / (1.0f + __expf(-x)));
  o[7] = (f16)0.0f;
  return o;
}

// Weight prep, PRE-SWIZZLED (rule 21): dim slot stored at (d&7)^(n&7) so a
// linear global_load_lds yields the swizzled LDS tile. Verified round 2.
__global__ __launch_bounds__(256)
void prep_w_kernel(const float* __restrict__ coef, const float* __restrict__ ssp,
                   const float* __restrict__ sb, f16* __restrict__ Wt,
                   int Din, int Dout) {
  int idx = blockIdx.x * 256 + threadIdx.x;
  if (idx >= Din * Dout) return;
  int n = idx / Din;
  int d = idx - n * Din;
  float s = ssp[(size_t)d * Dout + n];
  const float* c = coef + ((size_t)d * Dout + n) * 6;
  half8 wv;
#pragma unroll
  for (int b = 0; b < 6; ++b) wv[b] = (f16)(c[b] * s);
  wv[6] = (f16)sb[(size_t)d * Dout + n];
  wv[7] = (f16)0.0f;
  int dp = (d & ~7) | ((d & 7) ^ (n & 7));
  *reinterpret_cast<half8*>(Wt + ((size_t)n * Din + dp) * 8) = wv;
}

// ---------------------------------------------------------------------------
// Fused KAN GEMM, counted-vmcnt pipeline (race-fixed schedule).
// C[M,N] = expand(X)[M,8*Dsrc] x Wt[N,8*Dsrc]^T ; epilogue ns[col]*acc+nb[col].
// BM=64, BN=128, BK=64 (8 dims), 4 waves (2x2, 32x64 per wave), dbuf LDS 48KB.
// Invariant at every barrier: A(s+1)/B(s+1) tiles LANDED (each wave drained its
// own staging loads with vmcnt(2) BEFORE the barrier); only the 2 xb register
// loads (A floats for step s+2) ride across barriers.
// ---------------------------------------------------------------------------
__global__ __launch_bounds__(256, 3)
void kan_gemm(const float* __restrict__ Xsrc, int Dsrc,
              const f16* __restrict__ Wt,
              const float* __restrict__ nscale, const float* __restrict__ nbias,
              int N, float* __restrict__ Out) {
  __shared__ alignas(16) f16 lsA[2][64 * 64];    // 16 KB
  __shared__ alignas(16) f16 lsB[2][128 * 64];   // 32 KB

  const int tid  = threadIdx.x;
  const int w    = tid >> 6;
  const int lane = tid & 63;
  const int l15  = lane & 15, l7 = lane & 7, hi = lane >> 4;
  const int wm   = w >> 1, wn = w & 1;           // wave grid 2 x 2
  const int m0   = blockIdx.y * 64;
  const int n0   = blockIdx.x * 128;
  const int K    = Dsrc * 8;
  const int nsteps = Dsrc / 8;

  // A staging: 2 elements/thread (64 rows x 8 dims = 512 = 256*2)
  const int e1  = tid + 256;
  const int ar0 = tid >> 3, ad0 = tid & 7;
  const int ar1 = e1 >> 3,  ad1 = e1 & 7;
  const float* pA0 = Xsrc + (size_t)(m0 + ar0) * Dsrc + ad0;
  const float* pA1 = Xsrc + (size_t)(m0 + ar1) * Dsrc + ad1;
  const int aoff0 = ar0 * 64 + 8 * (ad0 ^ (ar0 & 7));
  const int aoff1 = ar1 * 64 + 8 * (ad1 ^ (ar1 & 7));

  // B staging: 4 x 16B chunks/thread (128 rows x 8 slots = 1024 chunks)
  const f16* wb[4];
  int ldsb[4];
#pragma unroll
  for (int q = 0; q < 4; ++q) {
    int c   = tid + q * 256;
    wb[q]   = Wt + (size_t)(n0 + (c >> 3)) * K + (c & 7) * 8;
    ldsb[q] = c * 8;
  }

  f32x4 acc[2][4] = {};

  auto stageB = [&](f16* buf, int k0) {
#pragma unroll
    for (int q = 0; q < 4; ++q) gload_lds16(wb[q] + k0, buf + ldsb[q]);
  };

  auto computeT = [&](const f16* bA, const f16* bB) {
#pragma unroll
    for (int kk = 0; kk < 2; ++kk) {
      const int sl = kk * 4 + hi;
      half8 av[2], bv[4];
#pragma unroll
      for (int i = 0; i < 2; ++i)
        av[i] = *reinterpret_cast<const half8*>(
            bA + (wm * 32 + i * 16 + l15) * 64 + 8 * (sl ^ l7));
#pragma unroll
      for (int j = 0; j < 4; ++j)
        bv[j] = *reinterpret_cast<const half8*>(
            bB + (wn * 64 + j * 16 + l15) * 64 + 8 * (sl ^ l7));
#pragma unroll
      for (int i = 0; i < 2; ++i)
#pragma unroll
        for (int j = 0; j < 4; ++j)
          acc[i][j] = __builtin_amdgcn_mfma_f32_16x16x32_f16(av[i], bv[j], acc[i][j], 0, 0, 0);
    }
  };

  // ---- prologue: establish invariant {A(0),B(0) landed; xb(1) in flight} ----
  float xa0 = pA0[0], xa1 = pA1[0];       // x(0) regs
  stageB(lsB[0], 0);                      // B(0): 4 gload_lds
  float xb0 = pA0[8], xb1 = pA1[8];       // x(1) regs (stay in flight)
  {
    // expand8 waits xa (older than B(0)/xb -> auto vmcnt(6))
    half8 h0 = expand8(xa0), h1 = expand8(xa1);
    *reinterpret_cast<half8*>(lsA[0] + aoff0) = h0;
    *reinterpret_cast<half8*>(lsA[0] + aoff1) = h1;
  }
  asm volatile("s_waitcnt vmcnt(2)" ::: "memory");   // B(0) landed, xb(1) rides
  asm volatile("s_waitcnt lgkmcnt(0)" ::: "memory"); // A(0) visible
  __builtin_amdgcn_sched_barrier(0);
  __builtin_amdgcn_s_barrier();

  const float* qA0 = pA0 + 16;            // x position for step s+2
  const float* qA1 = pA1 + 16;

  for (int s = 0; s < nsteps; ++s) {
    const int cur = s & 1, nxt = cur ^ 1;
    // 1) issue B(s+1) staging (clamped at tail: redundant but count-stable)
    const int kS = ((s + 1 < nsteps) ? (s + 1) : (nsteps - 1)) * 64;
    stageB(lsB[nxt], kS);
    // 2) expand A(s+1): auto-wait vmcnt(4) for xb regs (older than B(s+1))
    half8 h0 = expand8(xb0), h1 = expand8(xb1);
    // 3) issue x(s+2) reg loads (clamped at tail)
    xb0 = qA0[0]; xb1 = qA1[0];
    if (s + 3 < nsteps) { qA0 += 8; qA1 += 8; }
    // 4) compute on tile s — landed & barrier'd, no wait needed
    computeT(lsA[cur], lsB[cur]);
    // 5) publish A(s+1)
    *reinterpret_cast<half8*>(lsA[nxt] + aoff0) = h0;
    *reinterpret_cast<half8*>(lsA[nxt] + aoff1) = h1;
    // 6) drain OWN staging loads BEFORE the barrier (B(s+1)x4 done;
    //    only xb(s+2)x2 stay in flight). Then make LDS writes visible.
    asm volatile("s_waitcnt vmcnt(2)" ::: "memory");
    asm volatile("s_waitcnt lgkmcnt(0)" ::: "memory");
    __builtin_amdgcn_sched_barrier(0);
    __builtin_amdgcn_s_barrier();
    __builtin_amdgcn_sched_barrier(0);
  }

  // ---- epilogue ----
#pragma unroll
  for (int j = 0; j < 4; ++j) {
    int col  = n0 + wn * 64 + j * 16 + l15;
    float nsv = nscale[col], nbv = nbias[col];
#pragma unroll
    for (int i = 0; i < 2; ++i) {
      int rb = m0 + wm * 32 + i * 16 + hi * 4;
#pragma unroll
      for (int r = 0; r < 4; ++r)
        Out[(size_t)(rb + r) * N + col] = nsv * acc[i][j][r] + nbv;
    }
  }
}

// Residual + LayerNorm(256) + exact GELU, one wave per row, in place.
__global__ __launch_bounds__(256)
void ln_gelu_kernel(const float* __restrict__ T2, const float* __restrict__ X,
                    const float* __restrict__ gamma, const float* __restrict__ beta,
                    float* __restrict__ out, int rows) {
  int row  = blockIdx.x * 4 + (threadIdx.x >> 6);
  int lane = threadIdx.x & 63;
  if (row >= rows) return;
  const float* t2 = T2 + (size_t)row * 256;
  const float* xr = X  + (size_t)row * 256;
  float h[4];
  float s = 0.f;
#pragma unroll
  for (int j = 0; j < 4; ++j) {
    int c = j * 64 + lane;
    h[j]  = t2[c] + xr[c];
    s    += h[j];
  }
#pragma unroll
  for (int o = 32; o >= 1; o >>= 1) s += __shfl_xor(s, o);
  float mu = s * (1.0f / 256.0f);
  float vs = 0.f;
#pragma unroll
  for (int j = 0; j < 4; ++j) { float d = h[j] - mu; vs += d * d; }
#pragma unroll
  for (int o = 32; o >= 1; o >>= 1) vs += __shfl_xor(vs, o);
  float inv = rsqrtf(vs * (1.0f / 256.0f) + 1e-5f);
  float* orow = out + (size_t)row * 256;
#pragma unroll
  for (int j = 0; j < 4; ++j) {
    int c   = j * 64 + lane;
    float v = (h[j] - mu) * inv * gamma[c] + beta[c];
    orow[c] = 0.5f * v * (1.0f + erff(v * 0.70710678118654752f));
  }
}

// ---------------------------------------------------------------------------
extern "C" void kernel_launch(void* const* d_in, const int* in_sizes, int n_in,
                              void* d_out, int out_size, void* d_ws, size_t ws_size,
                              hipStream_t stream) {
  (void)in_sizes; (void)n_in; (void)out_size; (void)ws_size;
  const float* x     = (const float*)d_in[0];
  const float* coef1 = (const float*)d_in[2];
  const float* sb1   = (const float*)d_in[3];
  const float* ssp1  = (const float*)d_in[4];
  const float* ns1   = (const float*)d_in[5];
  const float* nb1   = (const float*)d_in[6];
  const float* coef2 = (const float*)d_in[8];
  const float* sb2   = (const float*)d_in[9];
  const float* ssp2  = (const float*)d_in[10];
  const float* ns2   = (const float*)d_in[11];
  const float* nb2   = (const float*)d_in[12];
  const float* lgam  = (const float*)d_in[13];
  const float* lbet  = (const float*)d_in[14];
  float* out = (float*)d_out;

  const int Ntok = 16 * 1024;
  const int D0 = 256, D1 = 512, D2 = 256;

  // ws: h1 [Ntok,512] f32 (33.5MB) | Wt1 2MB | Wt2 2MB
  char*  ws  = (char*)d_ws;
  float* h1  = (float*)ws;
  f16*   Wt1 = (f16*)(ws + (size_t)Ntok * D1 * sizeof(float));
  f16*   Wt2 = (f16*)(ws + (size_t)Ntok * D1 * sizeof(float) + (size_t)D1 * D0 * 8 * sizeof(f16));

  prep_w_kernel<<<(D0 * D1 + 255) / 256, 256, 0, stream>>>(coef1, ssp1, sb1, Wt1, D0, D1);
  prep_w_kernel<<<(D1 * D2 + 255) / 256, 256, 0, stream>>>(coef2, ssp2, sb2, Wt2, D1, D2);

  // layer 1: grid x=4 panels (4 | 8 -> one 512KB B-panel per XCD L2)
  kan_gemm<<<dim3(D1 / 128, Ntok / 64), 256, 0, stream>>>(x, D0, Wt1, ns1, nb1, D1, h1);

  // layer 2: grid x=2 panels (2 | 8 -> one 1MB B-panel per XCD L2)
  kan_gemm<<<dim3(D2 / 128, Ntok / 64), 256, 0, stream>>>(h1, D1, Wt2, ns2, nb2, D2, out);

  ln_gelu_kernel<<<Ntok / 4, 256, 0, stream>>>(out, x, lgam, lbet, out, Ntok);
}

// Round 5
// 232.232 us; speedup vs baseline: 1.4185x; 1.4185x over previous
//
#include <hip/hip_runtime.h>
#include <cstdint>
#include <cstddef>

using f16   = _Float16;
using half8 = __attribute__((ext_vector_type(8))) _Float16;
using f32x4 = __attribute__((ext_vector_type(4))) float;
using ull   = unsigned long long;

#define DINL __device__ __forceinline__

// pack two f32 -> two f16 (RTE, matches rounds 1-4 numerics) in one dword
DINL unsigned pkh(float a, float b) {
  unsigned short ha = __builtin_bit_cast(unsigned short, (f16)a);
  unsigned short hb = __builtin_bit_cast(unsigned short, (f16)b);
  return (unsigned)ha | ((unsigned)hb << 16);
}

struct U4 { unsigned x, y, z, w; };

// x -> 16B of A-row: channels [B0..B5, silu(x), 0] as 8 f16.
// Branchless: p0..p3 packed as 4 f16 in a 64-bit reg, funnel-shifted into a
// 128-bit window at channel (m-3). Spill past ch7 drops off the window;
// ch6/ch7 are overwritten with (silu, 0). Verified channel math: ch m-3..m
// get p0..p3 (same as the round-1..4 select chain, which passed at 0.03125).
DINL U4 expand_pack(float x) {
  float xs = (x + 3.0f) * 1.5f;        // (x - t0)/h, t0=-3, h=2/3
  float mf = floorf(xs);
  int   m  = (int)mf;
  float u = xs - mf, u2 = u * u, u3 = u2 * u, um = 1.0f - u;
  float p3 = u3 * (1.0f / 6.0f);
  float p2 = (1.0f + 3.0f * (u + u2 - u3)) * (1.0f / 6.0f);
  float p1 = (4.0f - 6.0f * u2 + 3.0f * u3) * (1.0f / 6.0f);
  float p0 = um * um * um * (1.0f / 6.0f);
  ull P = (ull)pkh(p0, p1) | ((ull)pkh(p2, p3) << 32);
  if ((unsigned)m > 8u) P = 0;         // outside [-3,3): all basis zero
  int s    = m * 16 - 48;              // bit shift = (m-3)*16, in [-48,80]
  int sneg = min(63, max(0, -s));
  int spos = min(63, max(0, s));
  int shi2 = min(63, max(0, s - 64));
  ull rlo = (s < 0) ? (P >> sneg) : ((s < 64) ? (P << spos) : 0ull);
  ull rhi = (s < 0) ? 0ull
                    : ((s < 64) ? ((P >> (63 - spos)) >> 1)   // == P >> (64-s), s=0 safe
                                : (P << shi2));
  float sil = x / (1.0f + __expf(-x));
  U4 r;
  r.x = (unsigned)rlo;
  r.y = (unsigned)(rlo >> 32);
  r.z = (unsigned)rhi;                 // ch4, ch5
  r.w = pkh(sil, 0.0f);                // ch6 = silu, ch7 = 0 (weight ch7 = 0)
  return r;
}

// ---------------------------------------------------------------------------
// Weight prep (plain [N][K] layout, K = Din*8): Wt[n][d*8+b] = coef[d][n][b]*ssp,
// ch6 = scale_base, ch7 = 0.
// ---------------------------------------------------------------------------
__global__ __launch_bounds__(256)
void prep_w_kernel(const float* __restrict__ coef, const float* __restrict__ ssp,
                   const float* __restrict__ sb, f16* __restrict__ Wt,
                   int Din, int Dout) {
  int idx = blockIdx.x * 256 + threadIdx.x;
  if (idx >= Din * Dout) return;
  int n = idx / Din;
  int d = idx - n * Din;
  float s = ssp[(size_t)d * Dout + n];
  const float* c = coef + ((size_t)d * Dout + n) * 6;
  half8 wv;
#pragma unroll
  for (int b = 0; b < 6; ++b) wv[b] = (f16)(c[b] * s);
  wv[6] = (f16)sb[(size_t)d * Dout + n];
  wv[7] = (f16)0.0f;
  *reinterpret_cast<half8*>(Wt + ((size_t)n * Din + d) * 8) = wv;
}

// ---------------------------------------------------------------------------
// One-wave fused KAN GEMM: 64x64 tile per wave, BK=64 (8 dims/step).
// NO barriers: A expand->LDS bounce is wave-synchronous (in-order DS);
// B fragments load global->VGPR (weights L2-resident).
// A LDS: 64 rows x 144B (128B data + 16B pad): bank = 4*row mod 32 ->
// conflict-free b128 frag reads, no swizzle needed.
// Split-K via blockIdx.z (partial outputs, deterministic).
// ---------------------------------------------------------------------------
template <bool BIAS>
__global__ __launch_bounds__(64, 2)
void kan_gemm(const float* __restrict__ X, int ldx,
              const f16* __restrict__ Wt, int ldw,
              const float* __restrict__ nscale, const float* __restrict__ nbias,
              int N, float* __restrict__ Out, int nsteps) {
  __shared__ alignas(16) char Alds[64 * 144];

  const int l    = threadIdx.x;
  const int l15  = l & 15, hi = l >> 4;
  const int m0   = blockIdx.y * 64;
  const int n0   = blockIdx.x * 64;
  const int dim0 = blockIdx.z * (nsteps * 8);
  float* outz = Out + (size_t)blockIdx.z * ((size_t)gridDim.y * 64) * N;

  const float* xp  = X + (size_t)(m0 + l) * ldx + dim0;
  const f16*   bp0 = Wt + (size_t)(n0 + l15) * ldw + dim0 * 8 + hi * 8;
  const f16*   bp1 = bp0 + (size_t)16 * ldw;
  const f16*   bp2 = bp0 + (size_t)32 * ldw;
  const f16*   bp3 = bp0 + (size_t)48 * ldw;

  char* wrow = Alds + l * 144;

  f32x4 acc[4][4] = {};

  for (int s = 0; s < nsteps; ++s) {
    // A source floats for this step (32B contiguous per lane)
    const float4 xf0 = *reinterpret_cast<const float4*>(xp + s * 8);
    const float4 xf1 = *reinterpret_cast<const float4*>(xp + s * 8 + 4);
    // B fragments straight to registers (8 x 16B); latency covered by expand
    const int ko = s * 64;
    half8 bv[2][4];
#pragma unroll
    for (int kk = 0; kk < 2; ++kk) {
      bv[kk][0] = *reinterpret_cast<const half8*>(bp0 + ko + kk * 32);
      bv[kk][1] = *reinterpret_cast<const half8*>(bp1 + ko + kk * 32);
      bv[kk][2] = *reinterpret_cast<const half8*>(bp2 + ko + kk * 32);
      bv[kk][3] = *reinterpret_cast<const half8*>(bp3 + ko + kk * 32);
    }
    // expand 8 elements -> 8 x 16B LDS slots (this wave's own rows)
    U4 e;
    e = expand_pack(xf0.x); *reinterpret_cast<U4*>(wrow +   0) = e;
    e = expand_pack(xf0.y); *reinterpret_cast<U4*>(wrow +  16) = e;
    e = expand_pack(xf0.z); *reinterpret_cast<U4*>(wrow +  32) = e;
    e = expand_pack(xf0.w); *reinterpret_cast<U4*>(wrow +  48) = e;
    e = expand_pack(xf1.x); *reinterpret_cast<U4*>(wrow +  64) = e;
    e = expand_pack(xf1.y); *reinterpret_cast<U4*>(wrow +  80) = e;
    e = expand_pack(xf1.z); *reinterpret_cast<U4*>(wrow +  96) = e;
    e = expand_pack(xf1.w); *reinterpret_cast<U4*>(wrow + 112) = e;
    // fragment reads + MFMA (compiler inserts lgkmcnt; DS is in-order per wave)
#pragma unroll
    for (int kk = 0; kk < 2; ++kk) {
      half8 av[4];
#pragma unroll
      for (int i = 0; i < 4; ++i)
        av[i] = *reinterpret_cast<const half8*>(
            Alds + (i * 16 + l15) * 144 + kk * 64 + hi * 16);
#pragma unroll
      for (int i = 0; i < 4; ++i)
#pragma unroll
        for (int j = 0; j < 4; ++j)
          acc[i][j] = __builtin_amdgcn_mfma_f32_16x16x32_f16(av[i], bv[kk][j],
                                                             acc[i][j], 0, 0, 0);
    }
  }

  // epilogue: Out = ns*acc (+ nb)
#pragma unroll
  for (int j = 0; j < 4; ++j) {
    int col   = n0 + j * 16 + l15;
    float nsv = nscale[col];
    float nbv = BIAS ? nbias[col] : 0.0f;
#pragma unroll
    for (int i = 0; i < 4; ++i) {
      int rb = m0 + i * 16 + hi * 4;
#pragma unroll
      for (int r = 0; r < 4; ++r)
        outz[(size_t)(rb + r) * N + col] = nsv * acc[i][j][r] + nbv;
    }
  }
}

// ---------------------------------------------------------------------------
// partial0 + partial1 + node_bias2 + residual -> LayerNorm(256) -> exact GELU
// ---------------------------------------------------------------------------
__global__ __launch_bounds__(256)
void ln_gelu_kernel(const float* __restrict__ P0, const float* __restrict__ P1,
                    const float* __restrict__ X,  const float* __restrict__ nb2,
                    const float* __restrict__ gamma, const float* __restrict__ beta,
                    float* __restrict__ out, int rows) {
  int row  = blockIdx.x * 4 + (threadIdx.x >> 6);
  int lane = threadIdx.x & 63;
  if (row >= rows) return;
  const float* p0 = P0 + (size_t)row * 256;
  const float* p1 = P1 + (size_t)row * 256;
  const float* xr = X  + (size_t)row * 256;
  float h[4];
  float s = 0.f;
#pragma unroll
  for (int j = 0; j < 4; ++j) {
    int c = j * 64 + lane;
    h[j]  = p0[c] + p1[c] + nb2[c] + xr[c];
    s    += h[j];
  }
#pragma unroll
  for (int o = 32; o >= 1; o >>= 1) s += __shfl_xor(s, o);
  float mu = s * (1.0f / 256.0f);
  float vs = 0.f;
#pragma unroll
  for (int j = 0; j < 4; ++j) { float d = h[j] - mu; vs += d * d; }
#pragma unroll
  for (int o = 32; o >= 1; o >>= 1) vs += __shfl_xor(vs, o);
  float inv = rsqrtf(vs * (1.0f / 256.0f) + 1e-5f);
  float* orow = out + (size_t)row * 256;
#pragma unroll
  for (int j = 0; j < 4; ++j) {
    int c   = j * 64 + lane;
    float v = (h[j] - mu) * inv * gamma[c] + beta[c];
    orow[c] = 0.5f * v * (1.0f + erff(v * 0.70710678118654752f));
  }
}

// ---------------------------------------------------------------------------
extern "C" void kernel_launch(void* const* d_in, const int* in_sizes, int n_in,
                              void* d_out, int out_size, void* d_ws, size_t ws_size,
                              hipStream_t stream) {
  (void)in_sizes; (void)n_in; (void)out_size; (void)ws_size;
  const float* x     = (const float*)d_in[0];
  const float* coef1 = (const float*)d_in[2];
  const float* sb1   = (const float*)d_in[3];
  const float* ssp1  = (const float*)d_in[4];
  const float* ns1   = (const float*)d_in[5];
  const float* nb1   = (const float*)d_in[6];
  const float* coef2 = (const float*)d_in[8];
  const float* sb2   = (const float*)d_in[9];
  const float* ssp2  = (const float*)d_in[10];
  const float* ns2   = (const float*)d_in[11];
  const float* nb2   = (const float*)d_in[12];
  const float* lgam  = (const float*)d_in[13];
  const float* lbet  = (const float*)d_in[14];
  float* out = (float*)d_out;

  const int Ntok = 16 * 1024;
  const int D0 = 256, D1 = 512, D2 = 256;

  // ws: h1 [Ntok,512] f32 (33.5MB) | part [2][Ntok,256] f32 (33.5MB) | Wt1 2MB | Wt2 2MB
  char*  ws   = (char*)d_ws;
  float* h1   = (float*)ws;
  size_t off  = (size_t)Ntok * D1 * sizeof(float);
  float* part = (float*)(ws + off);
  off += (size_t)2 * Ntok * D2 * sizeof(float);
  f16* Wt1 = (f16*)(ws + off);
  off += (size_t)D1 * D0 * 8 * sizeof(f16);
  f16* Wt2 = (f16*)(ws + off);

  prep_w_kernel<<<(D0 * D1 + 255) / 256, 256, 0, stream>>>(coef1, ssp1, sb1, Wt1, D0, D1);
  prep_w_kernel<<<(D1 * D2 + 255) / 256, 256, 0, stream>>>(coef2, ssp2, sb2, Wt2, D1, D2);

  // layer 1: [16384 x 2048] x [512 x 2048]^T -> h1 (2048 one-wave blocks)
  kan_gemm<true><<<dim3(D1 / 64, Ntok / 64, 1), 64, 0, stream>>>(
      x, D0, Wt1, D0 * 8, ns1, nb1, D1, h1, D0 / 8);

  // layer 2, split-K=2: partials ns2*acc (2048 one-wave blocks)
  kan_gemm<false><<<dim3(D2 / 64, Ntok / 64, 2), 64, 0, stream>>>(
      h1, D1, Wt2, D1 * 8, ns2, nullptr, D2, part, D1 / 16);

  // reduce partials + bias + residual + LN + GELU
  ln_gelu_kernel<<<Ntok / 4, 256, 0, stream>>>(
      part, part + (size_t)Ntok * D2, x, nb2, lgam, lbet, out, Ntok);
}

// Round 7
// 126.008 us; speedup vs baseline: 2.6143x; 1.8430x over previous
//
#include <hip/hip_runtime.h>
#include <cstdint>
#include <cstddef>

using f16   = _Float16;
using half8 = __attribute__((ext_vector_type(8))) _Float16;
using f32x4 = __attribute__((ext_vector_type(4))) float;
using ull   = unsigned long long;

#define DINL __device__ __forceinline__

// global -> LDS async, 16B per lane. LDS dest wave-uniform base + lane*16.
DINL void gload_lds16(const void* gptr, void* lptr) {
  __builtin_amdgcn_global_load_lds(
      reinterpret_cast<const __attribute__((address_space(1))) uint32_t*>(
          reinterpret_cast<uintptr_t>(gptr)),
      reinterpret_cast<__attribute__((address_space(3))) uint32_t*>(
          reinterpret_cast<uintptr_t>(lptr)),
      16, 0, 0);
}

DINL unsigned pkh(float a, float b) {
  unsigned short ha = __builtin_bit_cast(unsigned short, (f16)a);
  unsigned short hb = __builtin_bit_cast(unsigned short, (f16)b);
  return (unsigned)ha | ((unsigned)hb << 16);
}

struct U4 { unsigned x, y, z, w; };

// x -> 16B A-row: [B0..B5 uniform cubic B-spline, silu(x), 0] as 8 f16.
// Funnel-shift placement; validated round 5 (absmax 0.03125).
DINL U4 expand_pack(float x) {
  float xs = (x + 3.0f) * 1.5f;
  float mf = floorf(xs);
  int   m  = (int)mf;
  float u = xs - mf, u2 = u * u, u3 = u2 * u, um = 1.0f - u;
  float p3 = u3 * (1.0f / 6.0f);
  float p2 = (1.0f + 3.0f * (u + u2 - u3)) * (1.0f / 6.0f);
  float p1 = (4.0f - 6.0f * u2 + 3.0f * u3) * (1.0f / 6.0f);
  float p0 = um * um * um * (1.0f / 6.0f);
  ull P = (ull)pkh(p0, p1) | ((ull)pkh(p2, p3) << 32);
  if ((unsigned)m > 8u) P = 0;
  int s    = m * 16 - 48;
  int sneg = min(63, max(0, -s));
  int spos = min(63, max(0, s));
  int shi2 = min(63, max(0, s - 64));
  ull rlo = (s < 0) ? (P >> sneg) : ((s < 64) ? (P << spos) : 0ull);
  ull rhi = (s < 0) ? 0ull
                    : ((s < 64) ? ((P >> (63 - spos)) >> 1) : (P << shi2));
  float sil = x / (1.0f + __expf(-x));
  U4 r;
  r.x = (unsigned)rlo;
  r.y = (unsigned)(rlo >> 32);
  r.z = (unsigned)rhi;
  r.w = pkh(sil, 0.0f);
  return r;
}

// Weight prep, PRE-SWIZZLED (rule 21, validated round 2: 0 bank conflicts):
// dim slot stored at (d&7)^(n&7) so linear global_load_lds yields swizzled LDS.
__global__ __launch_bounds__(256)
void prep_w_kernel(const float* __restrict__ coef, const float* __restrict__ ssp,
                   const float* __restrict__ sb, f16* __restrict__ Wt,
                   int Din, int Dout) {
  int idx = blockIdx.x * 256 + threadIdx.x;
  if (idx >= Din * Dout) return;
  int n = idx / Din;
  int d = idx - n * Din;
  float s = ssp[(size_t)d * Dout + n];
  const float* c = coef + ((size_t)d * Dout + n) * 6;
  half8 wv;
#pragma unroll
  for (int b = 0; b < 6; ++b) wv[b] = (f16)(c[b] * s);
  wv[6] = (f16)sb[(size_t)d * Dout + n];
  wv[7] = (f16)0.0f;
  int dp = (d & ~7) | ((d & 7) ^ (n & 7));
  *reinterpret_cast<half8*>(Wt + ((size_t)n * Din + dp) * 8) = wv;
}

// ---------------------------------------------------------------------------
// Fused KAN GEMM v6b: BM=64 x BN=256, 8 waves (2x4 grid, 32x64 per wave),
// BK=64 (8 dims/step), double-buffered LDS (80KB -> 2 blocks/CU, 16 waves/CU),
// plain __syncthreads schedule (m97 pattern). Expansion done ONCE per block.
// Split-K via blockIdx.z writes partials. Buffer select via scalar ternary
// (pointer-array init of extern-shared addrspacecast doesn't compile).
// ---------------------------------------------------------------------------
template <bool BIAS>
__global__ __launch_bounds__(512, 2)
void kan_gemm(const float* __restrict__ X, int ldx,
              const f16* __restrict__ Wt, int ldw,
              const float* __restrict__ nscale, const float* __restrict__ nbias,
              int N, float* __restrict__ Out, int nsteps) {
  extern __shared__ char smem[];               // 81920 bytes
  f16* bufA0 = (f16*)smem;                     //  8 KB
  f16* bufA1 = (f16*)(smem + 8192);            //  8 KB
  f16* bufB0 = (f16*)(smem + 16384);           // 32 KB
  f16* bufB1 = (f16*)(smem + 16384 + 32768);   // 32 KB

  const int tid  = threadIdx.x;
  const int w    = tid >> 6;
  const int lane = tid & 63;
  const int l15  = lane & 15, l7 = lane & 7, hi = lane >> 4;
  const int wm   = w >> 2, wn = w & 3;         // wave grid 2 x 4
  const int m0   = blockIdx.y * 64;
  const int n0   = blockIdx.x * 256;
  const int dim0 = blockIdx.z * (nsteps * 8);  // split-K dim offset
  float* outz = Out + (size_t)blockIdx.z * ((size_t)gridDim.y * 64) * N;

  // A: 1 element/thread/step (64 rows x 8 dims = 512)
  const int ar = tid >> 3, ad = tid & 7;
  const float* asrc = X + (size_t)(m0 + ar) * ldx + dim0 + ad;
  const int aoff = ar * 64 + 8 * (ad ^ (ar & 7));

  // B: 4 x 16B chunks/thread (256 rows x 8 slots = 2048 chunks)
  const f16* wb[4];
  int ldsb[4];
#pragma unroll
  for (int q = 0; q < 4; ++q) {
    int c   = tid + q * 512;
    wb[q]   = Wt + (size_t)(n0 + (c >> 3)) * ldw + (size_t)dim0 * 8 + (c & 7) * 8;
    ldsb[q] = c * 8;
  }

  f32x4 acc[2][4] = {};

  auto stageB = [&](f16* buf, int k0) {
#pragma unroll
    for (int q = 0; q < 4; ++q) gload_lds16(wb[q] + k0, buf + ldsb[q]);
  };

  auto compute = [&](const f16* bA, const f16* bB) {
#pragma unroll
    for (int kk = 0; kk < 2; ++kk) {
      const int sl = kk * 4 + hi;
      half8 av[2], bv[4];
#pragma unroll
      for (int i = 0; i < 2; ++i)
        av[i] = *reinterpret_cast<const half8*>(
            bA + (wm * 32 + i * 16 + l15) * 64 + 8 * (sl ^ l7));
#pragma unroll
      for (int j = 0; j < 4; ++j)
        bv[j] = *reinterpret_cast<const half8*>(
            bB + (wn * 64 + j * 16 + l15) * 64 + 8 * (sl ^ l7));
#pragma unroll
      for (int i = 0; i < 2; ++i)
#pragma unroll
        for (int j = 0; j < 4; ++j)
          acc[i][j] = __builtin_amdgcn_mfma_f32_16x16x32_f16(av[i], bv[j], acc[i][j], 0, 0, 0);
    }
  };

  // prologue: tile 0 staged, x(1) prefetched
  {
    float xv = asrc[0];
    stageB(bufB0, 0);
    U4 e = expand_pack(xv);
    *reinterpret_cast<U4*>(bufA0 + aoff) = e;
  }
  float xn = asrc[8];
  __syncthreads();

  for (int s = 0; s < nsteps; ++s) {
    const bool odd = s & 1;
    f16* curA = odd ? bufA1 : bufA0;
    f16* curB = odd ? bufB1 : bufB0;
    f16* nxtA = odd ? bufA0 : bufA1;
    f16* nxtB = odd ? bufB0 : bufB1;
    if (s + 1 < nsteps) stageB(nxtB, (s + 1) * 64);               // async
    float xn2 = (s + 2 < nsteps) ? asrc[(size_t)(s + 2) * 8] : 0.0f; // issue early
    compute(curA, curB);                                          // MFMA stretch
    if (s + 1 < nsteps) {
      U4 e = expand_pack(xn);
      *reinterpret_cast<U4*>(nxtA + aoff) = e;
    }
    xn = xn2;
    __syncthreads();
  }

  // epilogue: Out = ns*acc (+ nb)
#pragma unroll
  for (int j = 0; j < 4; ++j) {
    int col   = n0 + wn * 64 + j * 16 + l15;
    float nsv = nscale[col];
    float nbv = BIAS ? nbias[col] : 0.0f;
#pragma unroll
    for (int i = 0; i < 2; ++i) {
      int rb = m0 + wm * 32 + i * 16 + hi * 4;
#pragma unroll
      for (int r = 0; r < 4; ++r)
        outz[(size_t)(rb + r) * N + col] = nsv * acc[i][j][r] + nbv;
    }
  }
}

// ---------------------------------------------------------------------------
// partial0 + partial1 + node_bias2 + residual -> LayerNorm(256) -> exact GELU
// ---------------------------------------------------------------------------
__global__ __launch_bounds__(256)
void ln_gelu_kernel(const float* __restrict__ P0, const float* __restrict__ P1,
                    const float* __restrict__ X,  const float* __restrict__ nb2,
                    const float* __restrict__ gamma, const float* __restrict__ beta,
                    float* __restrict__ out, int rows) {
  int row  = blockIdx.x * 4 + (threadIdx.x >> 6);
  int lane = threadIdx.x & 63;
  if (row >= rows) return;
  const float4 a  = *reinterpret_cast<const float4*>(P0 + (size_t)row * 256 + lane * 4);
  const float4 b  = *reinterpret_cast<const float4*>(P1 + (size_t)row * 256 + lane * 4);
  const float4 xr = *reinterpret_cast<const float4*>(X  + (size_t)row * 256 + lane * 4);
  const float4 nb = *reinterpret_cast<const float4*>(nb2 + lane * 4);
  const float4 g  = *reinterpret_cast<const float4*>(gamma + lane * 4);
  const float4 be = *reinterpret_cast<const float4*>(beta + lane * 4);
  float h[4] = { a.x + b.x + nb.x + xr.x, a.y + b.y + nb.y + xr.y,
                 a.z + b.z + nb.z + xr.z, a.w + b.w + nb.w + xr.w };
  float s = h[0] + h[1] + h[2] + h[3];
#pragma unroll
  for (int o = 32; o >= 1; o >>= 1) s += __shfl_xor(s, o);
  float mu = s * (1.0f / 256.0f);
  float vs = 0.f;
#pragma unroll
  for (int j = 0; j < 4; ++j) { float d = h[j] - mu; vs += d * d; }
#pragma unroll
  for (int o = 32; o >= 1; o >>= 1) vs += __shfl_xor(vs, o);
  float inv = rsqrtf(vs * (1.0f / 256.0f) + 1e-5f);
  float o4[4];
#pragma unroll
  for (int j = 0; j < 4; ++j) {
    float gj = (&g.x)[j], bj = (&be.x)[j];
    float v = (h[j] - mu) * inv * gj + bj;
    o4[j] = 0.5f * v * (1.0f + erff(v * 0.70710678118654752f));
  }
  *reinterpret_cast<float4*>(out + (size_t)row * 256 + lane * 4) =
      make_float4(o4[0], o4[1], o4[2], o4[3]);
}

// ---------------------------------------------------------------------------
extern "C" void kernel_launch(void* const* d_in, const int* in_sizes, int n_in,
                              void* d_out, int out_size, void* d_ws, size_t ws_size,
                              hipStream_t stream) {
  (void)in_sizes; (void)n_in; (void)out_size; (void)ws_size;
  const float* x     = (const float*)d_in[0];
  const float* coef1 = (const float*)d_in[2];
  const float* sb1   = (const float*)d_in[3];
  const float* ssp1  = (const float*)d_in[4];
  const float* ns1   = (const float*)d_in[5];
  const float* nb1   = (const float*)d_in[6];
  const float* coef2 = (const float*)d_in[8];
  const float* sb2   = (const float*)d_in[9];
  const float* ssp2  = (const float*)d_in[10];
  const float* ns2   = (const float*)d_in[11];
  const float* nb2   = (const float*)d_in[12];
  const float* lgam  = (const float*)d_in[13];
  const float* lbet  = (const float*)d_in[14];
  float* out = (float*)d_out;

  const int Ntok = 16 * 1024;
  const int D0 = 256, D1 = 512, D2 = 256;

  // ws: h1 [Ntok,512] f32 | part [2][Ntok,256] f32 | Wt1 2MB | Wt2 2MB
  char*  ws   = (char*)d_ws;
  float* h1   = (float*)ws;
  size_t off  = (size_t)Ntok * D1 * sizeof(float);
  float* part = (float*)(ws + off);
  off += (size_t)2 * Ntok * D2 * sizeof(float);
  f16* Wt1 = (f16*)(ws + off);
  off += (size_t)D1 * D0 * 8 * sizeof(f16);
  f16* Wt2 = (f16*)(ws + off);

  prep_w_kernel<<<(D0 * D1 + 255) / 256, 256, 0, stream>>>(coef1, ssp1, sb1, Wt1, D0, D1);
  prep_w_kernel<<<(D1 * D2 + 255) / 256, 256, 0, stream>>>(coef2, ssp2, sb2, Wt2, D1, D2);

  // layer 1: [16384 x 2048] x [512 x 2048]^T -> h1. 2 n-panels x 256 m = 512 blocks.
  kan_gemm<true><<<dim3(D1 / 256, Ntok / 64, 1), 512, 81920, stream>>>(
      x, D0, Wt1, D0 * 8, ns1, nb1, D1, h1, D0 / 8);

  // layer 2: full-width N=256, split-K=2 -> 512 blocks; partials ns2*acc.
  kan_gemm<false><<<dim3(D2 / 256, Ntok / 64, 2), 512, 81920, stream>>>(
      h1, D1, Wt2, D1 * 8, ns2, nullptr, D2, part, D1 / 16);

  // reduce partials + bias + residual + LN + GELU
  ln_gelu_kernel<<<Ntok / 4, 256, 0, stream>>>(
      part, part + (size_t)Ntok * D2, x, nb2, lgam, lbet, out, Ntok);
}

// Round 8
// 123.810 us; speedup vs baseline: 2.6607x; 1.0178x over previous
//
#include <hip/hip_runtime.h>
#include <cstdint>
#include <cstddef>

using f16   = _Float16;
using half8 = __attribute__((ext_vector_type(8))) _Float16;
using f32x4 = __attribute__((ext_vector_type(4))) float;
using ull   = unsigned long long;

#define DINL __device__ __forceinline__

// global -> LDS async, 16B per lane. LDS dest wave-uniform base + lane*16.
DINL void gload_lds16(const void* gptr, void* lptr) {
  __builtin_amdgcn_global_load_lds(
      reinterpret_cast<const __attribute__((address_space(1))) uint32_t*>(
          reinterpret_cast<uintptr_t>(gptr)),
      reinterpret_cast<__attribute__((address_space(3))) uint32_t*>(
          reinterpret_cast<uintptr_t>(lptr)),
      16, 0, 0);
}

DINL unsigned pkh(float a, float b) {
  unsigned short ha = __builtin_bit_cast(unsigned short, (f16)a);
  unsigned short hb = __builtin_bit_cast(unsigned short, (f16)b);
  return (unsigned)ha | ((unsigned)hb << 16);
}

struct U4 { unsigned x, y, z, w; };

// x -> 16B A-row: [B0..B5 uniform cubic B-spline, silu(x), 0] as 8 f16.
// Funnel-shift placement; validated rounds 5-7 (absmax 0.03125).
DINL U4 expand_pack(float x) {
  float xs = (x + 3.0f) * 1.5f;
  float mf = floorf(xs);
  int   m  = (int)mf;
  float u = xs - mf, u2 = u * u, u3 = u2 * u, um = 1.0f - u;
  float p3 = u3 * (1.0f / 6.0f);
  float p2 = (1.0f + 3.0f * (u + u2 - u3)) * (1.0f / 6.0f);
  float p1 = (4.0f - 6.0f * u2 + 3.0f * u3) * (1.0f / 6.0f);
  float p0 = um * um * um * (1.0f / 6.0f);
  ull P = (ull)pkh(p0, p1) | ((ull)pkh(p2, p3) << 32);
  if ((unsigned)m > 8u) P = 0;
  int s    = m * 16 - 48;
  int sneg = min(63, max(0, -s));
  int spos = min(63, max(0, s));
  int shi2 = min(63, max(0, s - 64));
  ull rlo = (s < 0) ? (P >> sneg) : ((s < 64) ? (P << spos) : 0ull);
  ull rhi = (s < 0) ? 0ull
                    : ((s < 64) ? ((P >> (63 - spos)) >> 1) : (P << shi2));
  float sil = x / (1.0f + __expf(-x));
  U4 r;
  r.x = (unsigned)rlo;
  r.y = (unsigned)(rlo >> 32);
  r.z = (unsigned)rhi;
  r.w = pkh(sil, 0.0f);
  return r;
}

// Weight prep, PRE-SWIZZLED (rule 21): dim slot stored at (d&7)^(n&7) so a
// linear global_load_lds yields the swizzled LDS tile. Validated rounds 2-7.
__global__ __launch_bounds__(256)
void prep_w_kernel(const float* __restrict__ coef, const float* __restrict__ ssp,
                   const float* __restrict__ sb, f16* __restrict__ Wt,
                   int Din, int Dout) {
  int idx = blockIdx.x * 256 + threadIdx.x;
  if (idx >= Din * Dout) return;
  int n = idx / Din;
  int d = idx - n * Din;
  float s = ssp[(size_t)d * Dout + n];
  const float* c = coef + ((size_t)d * Dout + n) * 6;
  half8 wv;
#pragma unroll
  for (int b = 0; b < 6; ++b) wv[b] = (f16)(c[b] * s);
  wv[6] = (f16)sb[(size_t)d * Dout + n];
  wv[7] = (f16)0.0f;
  int dp = (d & ~7) | ((d & 7) ^ (n & 7));
  *reinterpret_cast<half8*>(Wt + ((size_t)n * Din + dp) * 8) = wv;
}

// ---------------------------------------------------------------------------
// Fused KAN GEMM v8: identical structure/numerics to v6b (PASSED, absmax
// 0.03125), but K-loop unrolled x2 with STATIC buffer names + peeled tail:
// all LDS addresses are loop-invariant (base vaddr + imm offset), no ternary
// cndmasks, no per-iter branches. BM=64 x BN=256, 8 waves (2x4), BK=64,
// static __shared__ 80KB -> 2 blocks/CU. Split-K via blockIdx.z.
// ---------------------------------------------------------------------------
template <bool BIAS>
__global__ __launch_bounds__(512, 4)
void kan_gemm(const float* __restrict__ X, int ldx,
              const f16* __restrict__ Wt, int ldw,
              const float* __restrict__ nscale, const float* __restrict__ nbias,
              int N, float* __restrict__ Out, int nsteps) {
  __shared__ alignas(16) f16 A0[64 * 64];      //  8 KB
  __shared__ alignas(16) f16 A1[64 * 64];      //  8 KB
  __shared__ alignas(16) f16 B0[256 * 64];     // 32 KB
  __shared__ alignas(16) f16 B1[256 * 64];     // 32 KB

  const int tid  = threadIdx.x;
  const int w    = tid >> 6;
  const int lane = tid & 63;
  const int l15  = lane & 15, l7 = lane & 7, hi = lane >> 4;
  const int wm   = w >> 2, wn = w & 3;         // wave grid 2 x 4
  const int m0   = blockIdx.y * 64;
  const int n0   = blockIdx.x * 256;
  const int dim0 = blockIdx.z * (nsteps * 8);  // split-K dim offset
  float* outz = Out + (size_t)blockIdx.z * ((size_t)gridDim.y * 64) * N;

  // A: 1 element/thread/step (64 rows x 8 dims = 512)
  const int ar = tid >> 3, ad = tid & 7;
  const float* asrc = X + (size_t)(m0 + ar) * ldx + dim0 + ad;
  const int aoff = ar * 64 + 8 * (ad ^ (ar & 7));

  // B: 4 x 16B chunks/thread (256 rows x 8 slots = 2048 chunks)
  const f16* wb[4];
  int ldsb[4];
#pragma unroll
  for (int q = 0; q < 4; ++q) {
    int c   = tid + q * 512;
    wb[q]   = Wt + (size_t)(n0 + (c >> 3)) * ldw + (size_t)dim0 * 8 + (c & 7) * 8;
    ldsb[q] = c * 8;
  }

  f32x4 acc[2][4] = {};

  auto stageB = [&](f16* buf, int k0) {
#pragma unroll
    for (int q = 0; q < 4; ++q) gload_lds16(wb[q] + k0, buf + ldsb[q]);
  };

  auto compute = [&](const f16* bA, const f16* bB) {
#pragma unroll
    for (int kk = 0; kk < 2; ++kk) {
      const int sl = kk * 4 + hi;
      half8 av[2], bv[4];
#pragma unroll
      for (int i = 0; i < 2; ++i)
        av[i] = *reinterpret_cast<const half8*>(
            bA + (wm * 32 + i * 16 + l15) * 64 + 8 * (sl ^ l7));
#pragma unroll
      for (int j = 0; j < 4; ++j)
        bv[j] = *reinterpret_cast<const half8*>(
            bB + (wn * 64 + j * 16 + l15) * 64 + 8 * (sl ^ l7));
#pragma unroll
      for (int i = 0; i < 2; ++i)
#pragma unroll
        for (int j = 0; j < 4; ++j)
          acc[i][j] = __builtin_amdgcn_mfma_f32_16x16x32_f16(av[i], bv[j], acc[i][j], 0, 0, 0);
    }
  };

  auto writeA = [&](f16* buf, U4 e) {
    *reinterpret_cast<U4*>(buf + aoff) = e;
  };

  // ---- prologue: tile 0 in A0/B0; xn = x(1) in flight ----
  {
    float xa = asrc[0];
    stageB(B0, 0);
    writeA(A0, expand_pack(xa));
  }
  float xn = asrc[8];
  __syncthreads();

  // ---- steady state: 2 tiles per iteration, static buffers ----
  const float* ap = asrc + 16;                 // x(s+2) position
  const int npairs = (nsteps - 2) >> 1;
  int k = 64;                                  // staging k0 for tile s+1
  for (int p = 0; p < npairs; ++p) {
    // half A: compute tile s (A0/B0); stage B(s+1)->B1; expand x(s+1)->A1
    stageB(B1, k);
    float xa2 = ap[0];                         // x(s+2), issued early
    compute(A0, B0);
    writeA(A1, expand_pack(xn));
    __syncthreads();
    // half B: compute tile s+1 (A1/B1); stage B(s+2)->B0; expand x(s+2)->A0
    stageB(B0, k + 64);
    xn = ap[8];                                // x(s+3), issued early
    compute(A1, B1);
    writeA(A0, expand_pack(xa2));
    __syncthreads();
    ap += 16;
    k  += 128;
  }

  // ---- tail: tiles nsteps-2 (A0/B0) and nsteps-1 ----
  stageB(B1, k);                               // k == (nsteps-1)*64
  compute(A0, B0);
  writeA(A1, expand_pack(xn));
  __syncthreads();
  compute(A1, B1);

  // ---- epilogue: Out = ns*acc (+ nb) ----
#pragma unroll
  for (int j = 0; j < 4; ++j) {
    int col   = n0 + wn * 64 + j * 16 + l15;
    float nsv = nscale[col];
    float nbv = BIAS ? nbias[col] : 0.0f;
#pragma unroll
    for (int i = 0; i < 2; ++i) {
      int rb = m0 + wm * 32 + i * 16 + hi * 4;
#pragma unroll
      for (int r = 0; r < 4; ++r)
        outz[(size_t)(rb + r) * N + col] = nsv * acc[i][j][r] + nbv;
    }
  }
}

// ---------------------------------------------------------------------------
// partial0 + partial1 + node_bias2 + residual -> LayerNorm(256) -> exact GELU
// ---------------------------------------------------------------------------
__global__ __launch_bounds__(256)
void ln_gelu_kernel(const float* __restrict__ P0, const float* __restrict__ P1,
                    const float* __restrict__ X,  const float* __restrict__ nb2,
                    const float* __restrict__ gamma, const float* __restrict__ beta,
                    float* __restrict__ out, int rows) {
  int row  = blockIdx.x * 4 + (threadIdx.x >> 6);
  int lane = threadIdx.x & 63;
  if (row >= rows) return;
  const float4 a  = *reinterpret_cast<const float4*>(P0 + (size_t)row * 256 + lane * 4);
  const float4 b  = *reinterpret_cast<const float4*>(P1 + (size_t)row * 256 + lane * 4);
  const float4 xr = *reinterpret_cast<const float4*>(X  + (size_t)row * 256 + lane * 4);
  const float4 nb = *reinterpret_cast<const float4*>(nb2 + lane * 4);
  const float4 g  = *reinterpret_cast<const float4*>(gamma + lane * 4);
  const float4 be = *reinterpret_cast<const float4*>(beta + lane * 4);
  float h[4] = { a.x + b.x + nb.x + xr.x, a.y + b.y + nb.y + xr.y,
                 a.z + b.z + nb.z + xr.z, a.w + b.w + nb.w + xr.w };
  float s = h[0] + h[1] + h[2] + h[3];
#pragma unroll
  for (int o = 32; o >= 1; o >>= 1) s += __shfl_xor(s, o);
  float mu = s * (1.0f / 256.0f);
  float vs = 0.f;
#pragma unroll
  for (int j = 0; j < 4; ++j) { float d = h[j] - mu; vs += d * d; }
#pragma unroll
  for (int o = 32; o >= 1; o >>= 1) vs += __shfl_xor(vs, o);
  float inv = rsqrtf(vs * (1.0f / 256.0f) + 1e-5f);
  float o4[4];
#pragma unroll
  for (int j = 0; j < 4; ++j) {
    float gj = (&g.x)[j], bj = (&be.x)[j];
    float v = (h[j] - mu) * inv * gj + bj;
    o4[j] = 0.5f * v * (1.0f + erff(v * 0.70710678118654752f));
  }
  *reinterpret_cast<float4*>(out + (size_t)row * 256 + lane * 4) =
      make_float4(o4[0], o4[1], o4[2], o4[3]);
}

// ---------------------------------------------------------------------------
extern "C" void kernel_launch(void* const* d_in, const int* in_sizes, int n_in,
                              void* d_out, int out_size, void* d_ws, size_t ws_size,
                              hipStream_t stream) {
  (void)in_sizes; (void)n_in; (void)out_size; (void)ws_size;
  const float* x     = (const float*)d_in[0];
  const float* coef1 = (const float*)d_in[2];
  const float* sb1   = (const float*)d_in[3];
  const float* ssp1  = (const float*)d_in[4];
  const float* ns1   = (const float*)d_in[5];
  const float* nb1   = (const float*)d_in[6];
  const float* coef2 = (const float*)d_in[8];
  const float* sb2   = (const float*)d_in[9];
  const float* ssp2  = (const float*)d_in[10];
  const float* ns2   = (const float*)d_in[11];
  const float* nb2   = (const float*)d_in[12];
  const float* lgam  = (const float*)d_in[13];
  const float* lbet  = (const float*)d_in[14];
  float* out = (float*)d_out;

  const int Ntok = 16 * 1024;
  const int D0 = 256, D1 = 512, D2 = 256;

  // ws: h1 [Ntok,512] f32 | part [2][Ntok,256] f32 | Wt1 2MB | Wt2 2MB
  char*  ws   = (char*)d_ws;
  float* h1   = (float*)ws;
  size_t off  = (size_t)Ntok * D1 * sizeof(float);
  float* part = (float*)(ws + off);
  off += (size_t)2 * Ntok * D2 * sizeof(float);
  f16* Wt1 = (f16*)(ws + off);
  off += (size_t)D1 * D0 * 8 * sizeof(f16);
  f16* Wt2 = (f16*)(ws + off);

  prep_w_kernel<<<(D0 * D1 + 255) / 256, 256, 0, stream>>>(coef1, ssp1, sb1, Wt1, D0, D1);
  prep_w_kernel<<<(D1 * D2 + 255) / 256, 256, 0, stream>>>(coef2, ssp2, sb2, Wt2, D1, D2);

  // layer 1: [16384 x 2048] x [512 x 2048]^T -> h1. 2 n-panels x 256 m = 512 blocks.
  kan_gemm<true><<<dim3(D1 / 256, Ntok / 64, 1), 512, 0, stream>>>(
      x, D0, Wt1, D0 * 8, ns1, nb1, D1, h1, D0 / 8);

  // layer 2: full-width N=256, split-K=2 -> 512 blocks; partials ns2*acc.
  kan_gemm<false><<<dim3(D2 / 256, Ntok / 64, 2), 512, 0, stream>>>(
      h1, D1, Wt2, D1 * 8, ns2, nullptr, D2, part, D1 / 16);

  // reduce partials + bias + residual + LN + GELU
  ln_gelu_kernel<<<Ntok / 4, 256, 0, stream>>>(
      part, part + (size_t)Ntok * D2, x, nb2, lgam, lbet, out, Ntok);
}